// Round 1
// baseline (358.446 us; speedup 1.0000x reference)
//
#include <hip/hip_runtime.h>
#include <math.h>

#define ALPHA 0.2f
#define BETA 1.0f
#define EPSV 1e-8f

#define BATCH 4096
#define RR 18
#define KT 17            // R-1 targets per row
#define DD 256
#define NTGT (BATCH*KT)  // 69632 total targets

#define BMW 64           // anchors per wave (held in registers)
#define NWAVES 4
#define BMB (BMW*NWAVES) // 256 anchors per block
#define MBLK (BATCH/BMB) // 16
#define BN 64            // targets per LDS chunk
#define NSPLIT 32        // N-dimension splits
#define NSLICE (NTGT/NSPLIT) // 2176
#define NCHUNK (NSLICE/BN)   // 34
#define LDSP (DD+8)      // +8 bf16 pad = +16B: keeps 16B alignment, breaks bank aliasing

typedef __bf16 bf16x8 __attribute__((ext_vector_type(8)));
typedef float f32x4 __attribute__((ext_vector_type(4)));
typedef unsigned short ushortx8 __attribute__((ext_vector_type(8)));

__device__ inline unsigned short f2bf(float x){
  union { float f; unsigned int u; } v; v.f = x;
  unsigned int r = v.u + 0x7FFFu + ((v.u >> 16) & 1u);   // RNE
  return (unsigned short)(r >> 16);
}

__device__ inline ushortx8 cvt8(float4 f0, float4 f1){
  ushortx8 u;
  u[0]=f2bf(f0.x); u[1]=f2bf(f0.y); u[2]=f2bf(f0.z); u[3]=f2bf(f0.w);
  u[4]=f2bf(f1.x); u[5]=f2bf(f1.y); u[6]=f2bf(f1.z); u[7]=f2bf(f1.w);
  return u;
}

// ws layout (floats):
//   [0, 4096)                 diag dot (anchor·pos, fp32)
//   [4096, 4096+131072)       part_m  [4096][NSPLIT]
//   [135168, 135168+131072)   part_s  [4096][NSPLIT]
//   [266240], [266241]        acc_kl, acc_inf

// ---------------- Kernel 1: per-batch KL + diagonal dot (fp32 exact) ----------
__global__ __launch_bounds__(64) void prep_kernel(
    const float* __restrict__ feat, const float* __restrict__ scores,
    float* __restrict__ diag, float* __restrict__ accs){
  int b = blockIdx.x;
  int lane = threadIdx.x;
  const float* fb = feat + (size_t)b * RR * DD;
  float4 a4 = ((const float4*)fb)[lane];                 // anchor, 4 floats/lane
  float asq = a4.x*a4.x + a4.y*a4.y + a4.z*a4.z + a4.w*a4.w;
  #pragma unroll
  for (int off=1; off<64; off<<=1) asq += __shfl_xor(asq, off);
  float an = fmaxf(sqrtf(asq), EPSV);

  float cosv[KT];
  float dg = 0.f;
  #pragma unroll 1
  for (int k=1; k<=KT; ++k){
    float4 t4 = ((const float4*)(fb + k*DD))[lane];
    float d = a4.x*t4.x + a4.y*t4.y + a4.z*t4.z + a4.w*t4.w;
    float q = t4.x*t4.x + t4.y*t4.y + t4.z*t4.z + t4.w*t4.w;
    #pragma unroll
    for (int off=1; off<64; off<<=1){ d += __shfl_xor(d,off); q += __shfl_xor(q,off); }
    float tn = fmaxf(sqrtf(q), EPSV);
    cosv[k-1] = d / (an * tn);
    if (k==1) dg = d;
  }
  // log_softmax over cos (all lanes compute identically — no divergence)
  float cm = -INFINITY;
  #pragma unroll
  for (int j=0;j<KT;++j) cm = fmaxf(cm, cosv[j]);
  float cs = 0.f;
  #pragma unroll
  for (int j=0;j<KT;++j) cs += __expf(cosv[j]-cm);
  float lse_c = cm + __logf(cs);

  const float* sb = scores + (size_t)b*KT;
  float sv[KT];
  #pragma unroll
  for (int j=0;j<KT;++j) sv[j] = sb[j];
  float sm = -INFINITY;
  #pragma unroll
  for (int j=0;j<KT;++j) sm = fmaxf(sm, sv[j]);
  float ss = 0.f;
  #pragma unroll
  for (int j=0;j<KT;++j) ss += __expf(sv[j]-sm);
  float lse_s = sm + __logf(ss);

  float kl = 0.f;
  #pragma unroll
  for (int j=0;j<KT;++j){
    float lq = sv[j]   - lse_s;   // log ce
    float lp = cosv[j] - lse_c;   // emb_log
    kl += __expf(lq)*(lq - lp);
  }
  kl *= (1.0f/KT);
  if (lane==0){ diag[b]=dg; atomicAdd(accs+0, kl); }
}

// ---------------- Kernel 2: streaming bf16 MFMA GEMM + online logsumexp ------
// D[m=target][n=anchor]: targets are the A operand (LDS), anchors the B operand
// (persistent registers). Per-anchor reduction over targets = in-lane fold over
// regs + 2 shuffle steps (xor 16, 32).
__global__ __launch_bounds__(256,2) void gemm_lse_kernel(
    const float* __restrict__ feat, const float* __restrict__ lscale,
    float* __restrict__ part_m, float* __restrict__ part_s){
  __shared__ __align__(16) unsigned short Bs[BN][LDSP];
  const int tid  = threadIdx.x;
  const int lane = tid & 63;
  const int wave = tid >> 6;
  const int mb   = blockIdx.y;
  const int ns   = blockIdx.x;
  const float s  = lscale[0];
  const int l15  = lane & 15;
  const int quad = lane >> 4;

  // ---- stage anchors through LDS, capture B-operand frags in registers ----
  bf16x8 af[4][8];   // [ntile][kstep] : 64 anchors x 256 k per wave = 128 VGPRs
  for (int p=0; p<NWAVES; ++p){
    #pragma unroll
    for (int j=0;j<8;++j){
      int idx = tid + 256*j;            // 0..2047 = 64 rows x 32 groups of 8
      int r   = idx >> 5;
      int k8  = (idx & 31) << 3;
      size_t grow = (size_t)(mb*BMB + p*64 + r) * RR;   // anchor = row b*18
      const float* src = feat + grow*DD + k8;
      float4 f0 = ((const float4*)src)[0];
      float4 f1 = ((const float4*)src)[1];
      *(ushortx8*)&Bs[r][k8] = cvt8(f0,f1);
    }
    __syncthreads();
    if (wave == p){
      #pragma unroll
      for (int nt=0;nt<4;++nt)
        #pragma unroll
        for (int ks=0;ks<8;++ks)
          af[nt][ks] = *(const bf16x8*)&Bs[nt*16 + l15][ks*32 + quad*8];
    }
    __syncthreads();
  }

  float run_m[4] = {-INFINITY,-INFINITY,-INFINITY,-INFINITY};
  float run_s[4] = {0.f,0.f,0.f,0.f};
  const int tbase = ns*NSLICE;

  for (int ch=0; ch<NCHUNK; ++ch){
    // stage 64 targets (fp32 -> bf16) into LDS
    #pragma unroll
    for (int j=0;j<8;++j){
      int idx = tid + 256*j;
      int r   = idx >> 5;
      int k8  = (idx & 31) << 3;
      unsigned t  = (unsigned)(tbase + ch*BN + r);
      unsigned tb = t / 17u;
      unsigned tk = t - tb*17u;
      size_t grow = (size_t)tb*RR + tk + 1u;            // skip anchor row
      const float* src = feat + grow*DD + k8;
      float4 f0 = ((const float4*)src)[0];
      float4 f1 = ((const float4*)src)[1];
      *(ushortx8*)&Bs[r][k8] = cvt8(f0,f1);
    }
    __syncthreads();

    f32x4 acc[4][4];   // [mtile(target)][ntile(anchor)]
    #pragma unroll
    for (int mt=0;mt<4;++mt)
      #pragma unroll
      for (int nt=0;nt<4;++nt)
        acc[mt][nt] = (f32x4){0.f,0.f,0.f,0.f};

    #pragma unroll
    for (int ks=0;ks<8;++ks){
      bf16x8 tf[4];
      #pragma unroll
      for (int mt=0;mt<4;++mt)
        tf[mt] = *(const bf16x8*)&Bs[mt*16 + l15][ks*32 + quad*8];
      #pragma unroll
      for (int mt=0;mt<4;++mt)
        #pragma unroll
        for (int nt=0;nt<4;++nt)
          acc[mt][nt] = __builtin_amdgcn_mfma_f32_16x16x32_bf16(
                            tf[mt], af[nt][ks], acc[mt][nt], 0, 0, 0);
    }
    __syncthreads();   // Bs free; epilogue (registers only) overlaps next stage

    #pragma unroll
    for (int mt=0;mt<4;++mt)
      #pragma unroll
      for (int nt=0;nt<4;++nt)
        acc[mt][nt] = acc[mt][nt] * s;

    #pragma unroll
    for (int nt=0;nt<4;++nt){
      float mx = -INFINITY;
      #pragma unroll
      for (int mt=0;mt<4;++mt)
        #pragma unroll
        for (int r=0;r<4;++r)
          mx = fmaxf(mx, acc[mt][nt][r]);
      mx = fmaxf(mx, __shfl_xor(mx,16));
      mx = fmaxf(mx, __shfl_xor(mx,32));
      float sum = 0.f;
      #pragma unroll
      for (int mt=0;mt<4;++mt)
        #pragma unroll
        for (int r=0;r<4;++r)
          sum += __expf(acc[mt][nt][r] - mx);
      sum += __shfl_xor(sum,16);
      sum += __shfl_xor(sum,32);
      float nm = fmaxf(run_m[nt], mx);
      run_s[nt] = run_s[nt]*__expf(run_m[nt]-nm) + sum*__expf(mx-nm);
      run_m[nt] = nm;
    }
  }

  if (quad == 0){
    #pragma unroll
    for (int nt=0;nt<4;++nt){
      int gm = mb*BMB + wave*BMW + nt*16 + l15;
      part_m[(size_t)gm*NSPLIT + ns] = run_m[nt];
      part_s[(size_t)gm*NSPLIT + ns] = run_s[nt];
    }
  }
}

// ---------------- Kernel 3: combine per-split partials -> infonce sum --------
__global__ __launch_bounds__(256) void combine_kernel(
    const float* __restrict__ part_m, const float* __restrict__ part_s,
    const float* __restrict__ diag, const float* __restrict__ lscale,
    float* __restrict__ accs){
  int b = blockIdx.x*256 + threadIdx.x;
  float s = lscale[0];
  const float* pm = part_m + (size_t)b*NSPLIT;
  const float* ps = part_s + (size_t)b*NSPLIT;
  float M = -INFINITY;
  #pragma unroll
  for (int i=0;i<NSPLIT;++i) M = fmaxf(M, pm[i]);
  float S = 0.f;
  #pragma unroll
  for (int i=0;i<NSPLIT;++i) S += ps[i]*__expf(pm[i]-M);
  float inf = (M + __logf(S)) - s*diag[b];
  #pragma unroll
  for (int off=1; off<64; off<<=1) inf += __shfl_xor(inf, off);
  if ((threadIdx.x & 63)==0) atomicAdd(accs+1, inf);
}

// ---------------- Kernel 4: final scalar ------------------------------------
__global__ void final_kernel(const float* __restrict__ accs, float* __restrict__ out){
  out[0] = BETA*(accs[0]*(1.0f/BATCH)) + ALPHA*(accs[1]*(1.0f/BATCH));
}

extern "C" void kernel_launch(void* const* d_in, const int* in_sizes, int n_in,
                              void* d_out, int out_size, void* d_ws, size_t ws_size,
                              hipStream_t stream){
  const float* feat   = (const float*)d_in[0];
  const float* scores = (const float*)d_in[1];
  // d_in[2] row_sizes: shape-only in the reference, unused
  const float* lscale = (const float*)d_in[3];

  float* ws     = (float*)d_ws;
  float* diag   = ws;
  float* part_m = ws + BATCH;
  float* part_s = part_m + (size_t)BATCH*NSPLIT;
  float* accs   = part_s + (size_t)BATCH*NSPLIT;

  hipMemsetAsync(accs, 0, 2*sizeof(float), stream);
  prep_kernel<<<BATCH, 64, 0, stream>>>(feat, scores, diag, accs);
  gemm_lse_kernel<<<dim3(NSPLIT, MBLK), 256, 0, stream>>>(feat, lscale, part_m, part_s);
  combine_kernel<<<BATCH/256, 256, 0, stream>>>(part_m, part_s, diag, lscale, accs);
  final_kernel<<<1,1,0,stream>>>(accs, (float*)d_out);
}

// Round 2
// 320.284 us; speedup vs baseline: 1.1192x; 1.1192x over previous
//
#include <hip/hip_runtime.h>
#include <math.h>

#define ALPHA 0.2f
#define BETA 1.0f
#define EPSV 1e-8f
#define LOG2E 1.4426950408889634f

#define BATCH 4096
#define RR 18
#define KT 17            // R-1 targets per row
#define DD 256
#define NTGT (BATCH*KT)  // 69632 total targets

#define BMW 64           // anchors per wave (held in registers)
#define NWAVES 4
#define BMB (BMW*NWAVES) // 256 anchors per block
#define MBLK (BATCH/BMB) // 16
#define BN 64            // targets per LDS chunk
#define NSPLIT 32        // N-dimension splits
#define NSLICE (NTGT/NSPLIT) // 2176
#define NCHUNK (NSLICE/BN)   // 34
#define LDSP (DD+8)      // padded target row: 264 bf16 = 528 B (16B-aligned, breaks bank stride)
#define CHUNK_BYTES (BN*LDSP*2)  // 33792

typedef __bf16 bf16x8 __attribute__((ext_vector_type(8)));
typedef float f32x4 __attribute__((ext_vector_type(4)));

__device__ inline unsigned short f2bf(float x){
  union { float f; unsigned int u; } v; v.f = x;
  unsigned int r = v.u + 0x7FFFu + ((v.u >> 16) & 1u);   // RNE
  return (unsigned short)(r >> 16);
}

__device__ inline void gl_lds16(const void* g, void* l){
  __builtin_amdgcn_global_load_lds(
      (const __attribute__((address_space(1))) unsigned int*)g,
      (__attribute__((address_space(3))) unsigned int*)l, 16, 0, 0);
}

// ws layout (float offsets):
//   diag   @ 0            (4096)
//   part_m @ 4096         (4096*32)
//   part_s @ 135168       (4096*32)
//   accs   @ 266240       (4)   [kl, infonce]
//   abf    @ 266244       (4096*256 bf16 = 524288 f)  anchors pre-scaled by s
//   tbf    @ 790532       (69632*264 bf16)            compacted padded targets

// ---------------- Kernel 0: fp32 -> bf16 pre-convert (anchors scaled) --------
__global__ __launch_bounds__(256) void convert_kernel(
    const float* __restrict__ feat, const float* __restrict__ lscale,
    unsigned short* __restrict__ abf, unsigned short* __restrict__ tbf){
  int b = blockIdx.x, tid = threadIdx.x;
  float s = lscale[0];
  const float* fb = feat + (size_t)b * RR * DD;
  // anchor: 256 elements, one per thread, scaled by s
  abf[(size_t)b*DD + tid] = f2bf(fb[tid] * s);
  // targets: 17 rows x 64 float4 groups
  #pragma unroll 2
  for (int idx = tid; idx < KT*64; idx += 256){
    int r = idx >> 6, c4 = idx & 63;
    float4 v = ((const float4*)(fb + (size_t)(r+1)*DD))[c4];
    unsigned short* dst = tbf + ((size_t)b*KT + r)*LDSP + c4*4;
    unsigned short u0=f2bf(v.x), u1=f2bf(v.y), u2=f2bf(v.z), u3=f2bf(v.w);
    *(ushort4*)dst = make_ushort4(u0,u1,u2,u3);
  }
}

// ---------------- Kernel 1: per-batch KL + diagonal dot (fp32 exact) ---------
__global__ __launch_bounds__(256) void prep_kernel(
    const float* __restrict__ feat, const float* __restrict__ scores,
    float* __restrict__ diag, float* __restrict__ accs){
  __shared__ float csh[KT];
  int b = blockIdx.x, tid = threadIdx.x, lane = tid & 63, wave = tid >> 6;
  const float* fb = feat + (size_t)b * RR * DD;
  float4 a4 = ((const float4*)fb)[lane];
  float asq = a4.x*a4.x + a4.y*a4.y + a4.z*a4.z + a4.w*a4.w;
  #pragma unroll
  for (int off=1; off<64; off<<=1) asq += __shfl_xor(asq, off);
  float an = fmaxf(sqrtf(asq), EPSV);

  for (int k = wave+1; k <= KT; k += NWAVES){
    float4 t4 = ((const float4*)(fb + (size_t)k*DD))[lane];
    float d = a4.x*t4.x + a4.y*t4.y + a4.z*t4.z + a4.w*t4.w;
    float q = t4.x*t4.x + t4.y*t4.y + t4.z*t4.z + t4.w*t4.w;
    #pragma unroll
    for (int off=1; off<64; off<<=1){ d += __shfl_xor(d,off); q += __shfl_xor(q,off); }
    if (lane == 0){
      csh[k-1] = d / (an * fmaxf(sqrtf(q), EPSV));
      if (k == 1) diag[b] = d;
    }
  }
  __syncthreads();
  if (tid == 0){
    float cm = -INFINITY;
    #pragma unroll
    for (int j=0;j<KT;++j) cm = fmaxf(cm, csh[j]);
    float cs = 0.f;
    #pragma unroll
    for (int j=0;j<KT;++j) cs += __builtin_amdgcn_exp2f((csh[j]-cm)*LOG2E);
    float lse_c = cm + __logf(cs);

    const float* sb = scores + (size_t)b*KT;
    float sv[KT];
    #pragma unroll
    for (int j=0;j<KT;++j) sv[j] = sb[j];
    float sm = -INFINITY;
    #pragma unroll
    for (int j=0;j<KT;++j) sm = fmaxf(sm, sv[j]);
    float ss = 0.f;
    #pragma unroll
    for (int j=0;j<KT;++j) ss += __builtin_amdgcn_exp2f((sv[j]-sm)*LOG2E);
    float lse_s = sm + __logf(ss);

    float kl = 0.f;
    #pragma unroll
    for (int j=0;j<KT;++j){
      float lq = sv[j]  - lse_s;
      float lp = csh[j] - lse_c;
      kl += __builtin_amdgcn_exp2f(lq*LOG2E)*(lq - lp);
    }
    atomicAdd(accs+0, kl * (1.0f/KT));
  }
}

// ---------------- Kernel 2: streaming bf16 MFMA GEMM + online logsumexp ------
// D[m=target][n=anchor]. Targets staged via global_load_lds (pure DMA, bf16,
// padded rows). Anchors (pre-scaled by s) live in registers for the whole
// kernel. Per-anchor reduction over targets = in-register fold + 2 shuffles.
__global__ __launch_bounds__(256,2) void gemm_lse_kernel(
    const unsigned short* __restrict__ abf, const unsigned short* __restrict__ tbf,
    float* __restrict__ part_m, float* __restrict__ part_s){
  __shared__ __align__(16) unsigned short Bs[BN*LDSP];   // 33792 B
  const int tid  = threadIdx.x;
  const int lane = tid & 63;
  const int wave = tid >> 6;
  const int mb   = blockIdx.y;
  const int ns   = blockIdx.x;
  const int l15  = lane & 15;
  const int quad = lane >> 4;

  // anchor B-operand frags, straight from global bf16 (once per block)
  bf16x8 af[4][8];
  {
    const unsigned short* ab = abf + (size_t)(mb*BMB + wave*BMW)*DD;
    #pragma unroll
    for (int nt=0;nt<4;++nt)
      #pragma unroll
      for (int ks=0;ks<8;++ks)
        af[nt][ks] = *(const bf16x8*)(ab + (size_t)(nt*16+l15)*DD + ks*32 + quad*8);
  }

  const char* gbase = (const char*)(tbf + (size_t)(ns*NSLICE)*LDSP);
  char* lbase = (char*)Bs;
  auto stage = [&](int ch){
    const char* g = gbase + (size_t)ch*CHUNK_BYTES;
    #pragma unroll
    for (int j=0;j<8;++j){
      int off = j*4096 + tid*16;
      gl_lds16(g + off, lbase + off);
    }
    if (wave == 0){                      // tail: 33792-32768 = 1024 B
      int off = 32768 + lane*16;
      gl_lds16(g + off, lbase + off);
    }
  };

  stage(0);

  float run_m[4] = {-INFINITY,-INFINITY,-INFINITY,-INFINITY};
  float run_s[4] = {0.f,0.f,0.f,0.f};

  for (int ch=0; ch<NCHUNK; ++ch){
    __syncthreads();                     // DMA for ch drained (vmcnt0 at barrier)

    f32x4 acc[4][4];
    #pragma unroll
    for (int mt=0;mt<4;++mt)
      #pragma unroll
      for (int nt=0;nt<4;++nt)
        acc[mt][nt] = (f32x4){0.f,0.f,0.f,0.f};

    #pragma unroll
    for (int ks=0;ks<8;++ks){
      bf16x8 tf[4];
      #pragma unroll
      for (int mt=0;mt<4;++mt)
        tf[mt] = *(const bf16x8*)&Bs[(size_t)(mt*16+l15)*LDSP + ks*32 + quad*8];
      #pragma unroll
      for (int mt=0;mt<4;++mt)
        #pragma unroll
        for (int nt=0;nt<4;++nt)
          acc[mt][nt] = __builtin_amdgcn_mfma_f32_16x16x32_bf16(
                            tf[mt], af[nt][ks], acc[mt][nt], 0, 0, 0);
    }
    __syncthreads();                     // all Bs reads done
    if (ch+1 < NCHUNK) stage(ch+1);      // async DMA overlaps register epilogue

    // epilogue: online logsumexp, registers only
    #pragma unroll
    for (int nt=0;nt<4;++nt){
      f32x4 m01 = __builtin_elementwise_max(acc[0][nt], acc[1][nt]);
      f32x4 m23 = __builtin_elementwise_max(acc[2][nt], acc[3][nt]);
      f32x4 m4  = __builtin_elementwise_max(m01, m23);
      float mx = fmaxf(fmaxf(m4[0],m4[1]), fmaxf(m4[2],m4[3]));
      mx = fmaxf(mx, __shfl_xor(mx,16));
      mx = fmaxf(mx, __shfl_xor(mx,32));
      float c = mx*LOG2E;
      f32x4 sum4 = (f32x4){0.f,0.f,0.f,0.f};
      #pragma unroll
      for (int mt=0;mt<4;++mt){
        f32x4 t = acc[mt][nt]*LOG2E - c;   // v_pk_fma_f32
        f32x4 e;
        e[0]=__builtin_amdgcn_exp2f(t[0]); e[1]=__builtin_amdgcn_exp2f(t[1]);
        e[2]=__builtin_amdgcn_exp2f(t[2]); e[3]=__builtin_amdgcn_exp2f(t[3]);
        sum4 += e;
      }
      float sh = (sum4[0]+sum4[2])+(sum4[1]+sum4[3]);
      sh += __shfl_xor(sh,16);
      sh += __shfl_xor(sh,32);
      float nm = fmaxf(run_m[nt], mx);
      run_s[nt] = run_s[nt]*__builtin_amdgcn_exp2f((run_m[nt]-nm)*LOG2E)
                + sh*__builtin_amdgcn_exp2f((mx-nm)*LOG2E);
      run_m[nt] = nm;
    }
  }

  if (quad == 0){
    #pragma unroll
    for (int nt=0;nt<4;++nt){
      int gm = mb*BMB + wave*BMW + nt*16 + l15;
      part_m[(size_t)gm*NSPLIT + ns] = run_m[nt];
      part_s[(size_t)gm*NSPLIT + ns] = run_s[nt];
    }
  }
}

// ---------------- Kernel 3: combine per-split partials -> infonce sum --------
__global__ __launch_bounds__(256) void combine_kernel(
    const float* __restrict__ part_m, const float* __restrict__ part_s,
    const float* __restrict__ diag, const float* __restrict__ lscale,
    float* __restrict__ accs){
  int b = blockIdx.x*256 + threadIdx.x;
  float s = lscale[0];
  const float* pm = part_m + (size_t)b*NSPLIT;
  const float* ps = part_s + (size_t)b*NSPLIT;
  float M = -INFINITY;
  #pragma unroll
  for (int i=0;i<NSPLIT;++i) M = fmaxf(M, pm[i]);
  float S = 0.f;
  #pragma unroll
  for (int i=0;i<NSPLIT;++i) S += ps[i]*__builtin_amdgcn_exp2f((pm[i]-M)*LOG2E);
  float inf = (M + __logf(S)) - s*diag[b];
  #pragma unroll
  for (int off=1; off<64; off<<=1) inf += __shfl_xor(inf, off);
  if ((threadIdx.x & 63)==0) atomicAdd(accs+1, inf);
}

// ---------------- Kernel 4: final scalar ------------------------------------
__global__ void final_kernel(const float* __restrict__ accs, float* __restrict__ out){
  out[0] = BETA*(accs[0]*(1.0f/BATCH)) + ALPHA*(accs[1]*(1.0f/BATCH));
}

extern "C" void kernel_launch(void* const* d_in, const int* in_sizes, int n_in,
                              void* d_out, int out_size, void* d_ws, size_t ws_size,
                              hipStream_t stream){
  const float* feat   = (const float*)d_in[0];
  const float* scores = (const float*)d_in[1];
  // d_in[2] row_sizes: shape-only, unused
  const float* lscale = (const float*)d_in[3];

  float* ws     = (float*)d_ws;
  float* diag   = ws;                                   // 4096
  float* part_m = ws + 4096;                            // 131072
  float* part_s = part_m + (size_t)BATCH*NSPLIT;        // 131072
  float* accs   = part_s + (size_t)BATCH*NSPLIT;        // 4
  unsigned short* abf = (unsigned short*)(accs + 4);    // 4096*256 bf16
  unsigned short* tbf = abf + (size_t)BATCH*DD;         // 69632*264 bf16

  hipMemsetAsync(accs, 0, 2*sizeof(float), stream);
  convert_kernel<<<BATCH, 256, 0, stream>>>(feat, lscale, abf, tbf);
  prep_kernel<<<BATCH, 256, 0, stream>>>(feat, scores, diag, accs);
  gemm_lse_kernel<<<dim3(NSPLIT, MBLK), 256, 0, stream>>>(abf, tbf, part_m, part_s);
  combine_kernel<<<BATCH/256, 256, 0, stream>>>(part_m, part_s, diag, lscale, accs);
  final_kernel<<<1,1,0,stream>>>(accs, (float*)d_out);
}

// Round 3
// 306.396 us; speedup vs baseline: 1.1699x; 1.0453x over previous
//
#include <hip/hip_runtime.h>
#include <math.h>

#define ALPHA 0.2f
#define BETA 1.0f
#define EPSV 1e-8f
#define LOG2E 1.4426950408889634f
#define LN2 0.6931471805599453f

#define BATCH 4096
#define RR 18
#define KT 17            // R-1 targets per row
#define DD 256
#define NTGT (BATCH*KT)  // 69632 total targets

#define BMW 64           // anchors per wave (2 x 32-tiles, frags in registers)
#define NWAVES 4
#define BMB (BMW*NWAVES) // 256 anchors per block
#define MBLK (BATCH/BMB) // 16
#define BN 64            // targets per LDS chunk
#define NSPLIT 32        // N-dimension splits
#define NSLICE (NTGT/NSPLIT) // 2176
#define NCHUNK (NSLICE/BN)   // 34
#define LDSP (DD+8)      // padded target row: 264 bf16 = 528 B
#define CHUNK_BYTES (BN*LDSP*2)  // 33792

typedef __bf16 bf16x8 __attribute__((ext_vector_type(8)));
typedef float f32x16 __attribute__((ext_vector_type(16)));

__device__ inline unsigned short f2bf(float x){
  union { float f; unsigned int u; } v; v.f = x;
  unsigned int r = v.u + 0x7FFFu + ((v.u >> 16) & 1u);   // RNE
  return (unsigned short)(r >> 16);
}

__device__ inline void gl_lds16(const void* g, void* l){
  __builtin_amdgcn_global_load_lds(
      (const __attribute__((address_space(1))) unsigned int*)g,
      (__attribute__((address_space(3))) unsigned int*)l, 16, 0, 0);
}

// ws layout (float offsets):
//   diag   @ 0            (4096)              raw fp32 anchor·pos
//   part_m @ 4096         (4096*32)           log2-domain running max
//   part_s @ 135168       (4096*32)           sum of 2^(x-m)
//   accs   @ 266240       (4)                 [kl, infonce]
//   abf    @ 266244       anchors bf16, pre-scaled by s*log2e
//   tbf    @ ...          compacted padded bf16 targets [69632][264]

// ---------------- Kernel 1: fused convert + KL + diag (single input read) ----
__global__ __launch_bounds__(256) void prep_kernel(
    const float* __restrict__ feat, const float* __restrict__ scores,
    const float* __restrict__ lscale,
    unsigned short* __restrict__ abf, unsigned short* __restrict__ tbf,
    float* __restrict__ diag, float* __restrict__ accs){
  __shared__ float csh[KT];
  int b = blockIdx.x, tid = threadIdx.x, lane = tid & 63, wave = tid >> 6;
  const float* fb = feat + (size_t)b * RR * DD;
  float s2 = lscale[0] * LOG2E;

  // anchor: every wave loads + reduces (L1-broadcast; no sync needed)
  float4 a4 = ((const float4*)fb)[lane];
  float asq = a4.x*a4.x + a4.y*a4.y + a4.z*a4.z + a4.w*a4.w;
  #pragma unroll
  for (int off=1; off<64; off<<=1) asq += __shfl_xor(asq, off);
  float an = fmaxf(sqrtf(asq), EPSV);

  // bf16 anchor out, scaled into log2 domain
  abf[(size_t)b*DD + tid] = f2bf(fb[tid] * s2);

  // target rows: wave w handles k = w+1, w+5, ...
  for (int k = wave+1; k <= KT; k += NWAVES){
    float4 t4 = ((const float4*)(fb + (size_t)k*DD))[lane];
    unsigned short* dst = tbf + ((size_t)b*KT + (k-1))*LDSP + lane*4;
    *(ushort4*)dst = make_ushort4(f2bf(t4.x), f2bf(t4.y), f2bf(t4.z), f2bf(t4.w));
    float d = a4.x*t4.x + a4.y*t4.y + a4.z*t4.z + a4.w*t4.w;
    float q = t4.x*t4.x + t4.y*t4.y + t4.z*t4.z + t4.w*t4.w;
    #pragma unroll
    for (int off=1; off<64; off<<=1){ d += __shfl_xor(d,off); q += __shfl_xor(q,off); }
    if (lane == 0){
      csh[k-1] = d / (an * fmaxf(sqrtf(q), EPSV));
      if (k == 1) diag[b] = d;
    }
  }
  __syncthreads();
  if (tid == 0){
    float cm = -INFINITY;
    #pragma unroll
    for (int j=0;j<KT;++j) cm = fmaxf(cm, csh[j]);
    float cs = 0.f;
    #pragma unroll
    for (int j=0;j<KT;++j) cs += __builtin_amdgcn_exp2f((csh[j]-cm)*LOG2E);
    float lse_c = cm + __logf(cs);

    const float* sb = scores + (size_t)b*KT;
    float sv[KT];
    #pragma unroll
    for (int j=0;j<KT;++j) sv[j] = sb[j];
    float sm = -INFINITY;
    #pragma unroll
    for (int j=0;j<KT;++j) sm = fmaxf(sm, sv[j]);
    float ss = 0.f;
    #pragma unroll
    for (int j=0;j<KT;++j) ss += __builtin_amdgcn_exp2f((sv[j]-sm)*LOG2E);
    float lse_s = sm + __logf(ss);

    float kl = 0.f;
    #pragma unroll
    for (int j=0;j<KT;++j){
      float lq = sv[j]  - lse_s;
      float lp = csh[j] - lse_c;
      kl += __builtin_amdgcn_exp2f(lq*LOG2E)*(lq - lp);
    }
    atomicAdd(accs+0, kl * (1.0f/KT));
  }
}

// ---------------- Kernel 2: 32x32x16 MFMA GEMM + online log2-sum-exp2 --------
// D[m=target][n=anchor]. Targets staged via global_load_lds DMA; anchors
// (scaled by s*log2e) persistent in registers (2 n-tiles x 16 K-steps).
// C/D layout 32x32: col=lane&31, row=(reg&3)+8*(reg>>2)+4*(lane>>5).
// Per-anchor reduction over targets = 32-reg in-lane fold + ONE shfl_xor(32).
__global__ __launch_bounds__(256,2) void gemm_lse_kernel(
    const unsigned short* __restrict__ abf, const unsigned short* __restrict__ tbf,
    float* __restrict__ part_m, float* __restrict__ part_s){
  __shared__ __align__(16) unsigned short Bs[BN*LDSP];   // 33792 B
  const int tid  = threadIdx.x;
  const int lane = tid & 63;
  const int wave = tid >> 6;
  const int mb   = blockIdx.y;
  const int ns   = blockIdx.x;
  const int l31  = lane & 31;
  const int half = lane >> 5;

  // anchor B-operand frags (once per block): n=lane&31, k=half*8+j
  bf16x8 af[2][16];
  {
    const unsigned short* ab = abf + (size_t)(mb*BMB + wave*BMW)*DD;
    #pragma unroll
    for (int nt=0;nt<2;++nt)
      #pragma unroll
      for (int ks=0;ks<16;++ks)
        af[nt][ks] = *(const bf16x8*)(ab + (size_t)(nt*32+l31)*DD + ks*16 + half*8);
  }

  const char* gbase = (const char*)(tbf + (size_t)(ns*NSLICE)*LDSP);
  char* lbase = (char*)Bs;
  auto stage = [&](int ch){
    const char* g = gbase + (size_t)ch*CHUNK_BYTES;
    #pragma unroll
    for (int j=0;j<8;++j){
      int off = j*4096 + tid*16;
      gl_lds16(g + off, lbase + off);
    }
    if (wave == 0){                      // tail: 33792-32768 = 1024 B
      int off = 32768 + lane*16;
      gl_lds16(g + off, lbase + off);
    }
  };

  stage(0);

  float run_m[2] = {-INFINITY,-INFINITY};
  float run_s[2] = {0.f,0.f};

  for (int ch=0; ch<NCHUNK; ++ch){
    __syncthreads();                     // DMA for ch drained

    f32x16 acc[2][2];                    // [mtile(target)][ntile(anchor)]
    #pragma unroll
    for (int mt=0;mt<2;++mt)
      #pragma unroll
      for (int nt=0;nt<2;++nt)
        acc[mt][nt] = (f32x16)(0.f);

    #pragma unroll
    for (int ks=0;ks<16;++ks){
      bf16x8 tf0 = *(const bf16x8*)&Bs[(size_t)(     l31)*LDSP + ks*16 + half*8];
      bf16x8 tf1 = *(const bf16x8*)&Bs[(size_t)(32 + l31)*LDSP + ks*16 + half*8];
      acc[0][0] = __builtin_amdgcn_mfma_f32_32x32x16_bf16(tf0, af[0][ks], acc[0][0], 0,0,0);
      acc[0][1] = __builtin_amdgcn_mfma_f32_32x32x16_bf16(tf0, af[1][ks], acc[0][1], 0,0,0);
      acc[1][0] = __builtin_amdgcn_mfma_f32_32x32x16_bf16(tf1, af[0][ks], acc[1][0], 0,0,0);
      acc[1][1] = __builtin_amdgcn_mfma_f32_32x32x16_bf16(tf1, af[1][ks], acc[1][1], 0,0,0);
    }
    __syncthreads();                     // all Bs reads done
    if (ch+1 < NCHUNK) stage(ch+1);      // async DMA overlaps register epilogue

    // epilogue (log2 domain): per anchor col, fold 32 regs + 1 shuffle
    #pragma unroll
    for (int nt=0;nt<2;++nt){
      f32x16 t = __builtin_elementwise_max(acc[0][nt], acc[1][nt]);
      float m8[8];
      #pragma unroll
      for (int i=0;i<8;++i) m8[i] = fmaxf(t[i], t[i+8]);
      float m4a = fmaxf(m8[0],m8[1]), m4b = fmaxf(m8[2],m8[3]);
      float m4c = fmaxf(m8[4],m8[5]), m4d = fmaxf(m8[6],m8[7]);
      float mx = fmaxf(fmaxf(m4a,m4b), fmaxf(m4c,m4d));
      mx = fmaxf(mx, __shfl_xor(mx, 32));

      float s0=0.f, s1=0.f, s2=0.f, s3=0.f;
      #pragma unroll
      for (int r=0;r<16;r+=4){
        s0 += __builtin_amdgcn_exp2f(acc[0][nt][r  ]-mx) + __builtin_amdgcn_exp2f(acc[1][nt][r  ]-mx);
        s1 += __builtin_amdgcn_exp2f(acc[0][nt][r+1]-mx) + __builtin_amdgcn_exp2f(acc[1][nt][r+1]-mx);
        s2 += __builtin_amdgcn_exp2f(acc[0][nt][r+2]-mx) + __builtin_amdgcn_exp2f(acc[1][nt][r+2]-mx);
        s3 += __builtin_amdgcn_exp2f(acc[0][nt][r+3]-mx) + __builtin_amdgcn_exp2f(acc[1][nt][r+3]-mx);
      }
      float sh = (s0+s1)+(s2+s3);
      sh += __shfl_xor(sh, 32);

      float nm = fmaxf(run_m[nt], mx);
      run_s[nt] = run_s[nt]*__builtin_amdgcn_exp2f(run_m[nt]-nm)
                + sh*__builtin_amdgcn_exp2f(mx-nm);
      run_m[nt] = nm;
    }
  }

  if (half == 0){                        // lanes 0..31 hold the full reduction
    #pragma unroll
    for (int nt=0;nt<2;++nt){
      int gm = mb*BMB + wave*BMW + nt*32 + l31;
      part_m[(size_t)gm*NSPLIT + ns] = run_m[nt];
      part_s[(size_t)gm*NSPLIT + ns] = run_s[nt];
    }
  }
}

// ---------------- Kernel 3: combine per-split partials -> infonce sum --------
__global__ __launch_bounds__(256) void combine_kernel(
    const float* __restrict__ part_m, const float* __restrict__ part_s,
    const float* __restrict__ diag, const float* __restrict__ lscale,
    float* __restrict__ accs){
  int b = blockIdx.x*256 + threadIdx.x;
  float s = lscale[0];
  const float* pm = part_m + (size_t)b*NSPLIT;
  const float* ps = part_s + (size_t)b*NSPLIT;
  float M = -INFINITY;
  #pragma unroll
  for (int i=0;i<NSPLIT;++i) M = fmaxf(M, pm[i]);
  float S = 0.f;
  #pragma unroll
  for (int i=0;i<NSPLIT;++i) S += ps[i]*__builtin_amdgcn_exp2f(pm[i]-M);
  float inf = (M + __log2f(S))*LN2 - s*diag[b];   // back to ln domain
  #pragma unroll
  for (int off=1; off<64; off<<=1) inf += __shfl_xor(inf, off);
  if ((threadIdx.x & 63)==0) atomicAdd(accs+1, inf);
}

// ---------------- Kernel 4: final scalar ------------------------------------
__global__ void final_kernel(const float* __restrict__ accs, float* __restrict__ out){
  out[0] = BETA*(accs[0]*(1.0f/BATCH)) + ALPHA*(accs[1]*(1.0f/BATCH));
}

extern "C" void kernel_launch(void* const* d_in, const int* in_sizes, int n_in,
                              void* d_out, int out_size, void* d_ws, size_t ws_size,
                              hipStream_t stream){
  const float* feat   = (const float*)d_in[0];
  const float* scores = (const float*)d_in[1];
  // d_in[2] row_sizes: shape-only, unused
  const float* lscale = (const float*)d_in[3];

  float* ws     = (float*)d_ws;
  float* diag   = ws;                                   // 4096
  float* part_m = ws + 4096;                            // 131072
  float* part_s = part_m + (size_t)BATCH*NSPLIT;        // 131072
  float* accs   = part_s + (size_t)BATCH*NSPLIT;        // 4
  unsigned short* abf = (unsigned short*)(accs + 4);    // 4096*256 bf16
  unsigned short* tbf = abf + (size_t)BATCH*DD;         // 69632*264 bf16

  hipMemsetAsync(accs, 0, 2*sizeof(float), stream);
  prep_kernel<<<BATCH, 256, 0, stream>>>(feat, scores, lscale, abf, tbf, diag, accs);
  gemm_lse_kernel<<<dim3(NSPLIT, MBLK), 256, 0, stream>>>(abf, tbf, part_m, part_s);
  combine_kernel<<<BATCH/256, 256, 0, stream>>>(part_m, part_s, diag, lscale, accs);
  final_kernel<<<1,1,0,stream>>>(accs, (float*)d_out);
}

// Round 4
// 277.489 us; speedup vs baseline: 1.2917x; 1.1042x over previous
//
#include <hip/hip_runtime.h>
#include <math.h>

#define ALPHA 0.2f
#define BETA 1.0f
#define EPSV 1e-8f
#define LOG2E 1.4426950408889634f
#define LN2 0.6931471805599453f

#define BATCH 4096
#define RR 18
#define KT 17            // R-1 targets per row
#define DD 256
#define NTGT (BATCH*KT)  // 69632 total targets

#define BMW 64           // anchors per wave (2 x 32-tiles, frags in registers)
#define NWAVES 4
#define BMB (BMW*NWAVES) // 256 anchors per block
#define MBLK (BATCH/BMB) // 16
#define BN 64            // targets per LDS chunk
#define NSPLIT 32        // N-dimension splits
#define NSLOT (NSPLIT*2) // per-anchor partial slots (x2: per half-wave)
#define NSLICE (NTGT/NSPLIT) // 2176
#define NCHUNK (NSLICE/BN)   // 34
#define CHUNK_BYTES (BN*DD*2)    // 32768, fragment-ordered, no padding

typedef __bf16 bf16x8 __attribute__((ext_vector_type(8)));
typedef float f32x16 __attribute__((ext_vector_type(16)));

__device__ inline unsigned short f2bf(float x){
  union { float f; unsigned int u; } v; v.f = x;
  unsigned int r = v.u + 0x7FFFu + ((v.u >> 16) & 1u);   // RNE
  return (unsigned short)(r >> 16);
}

__device__ inline void gl_lds16(const void* g, void* l){
  __builtin_amdgcn_global_load_lds(
      (const __attribute__((address_space(1))) unsigned int*)g,
      (__attribute__((address_space(3))) unsigned int*)l, 16, 0, 0);
}

// tbf layout (fragment-ordered): target t -> chunk c=t>>6, row r=t&63,
// mt=r>>5, r31=r&31. Fragment (c,mt,ks) is 1 KB: 64 lanes x 16 B, where
// gemm lane l = h*32 + r31 holds A[m=mt*32+r31][k=ks*16+h*8 .. +8].
// Chunk c = contiguous 32 KB at tbf + c*32KB. DMA = pure linear copy.

// ---------------- Kernel 1: fused convert(+swizzle) + KL + diag --------------
__global__ __launch_bounds__(256) void prep_kernel(
    const float* __restrict__ feat, const float* __restrict__ scores,
    const float* __restrict__ lscale,
    unsigned short* __restrict__ abf, unsigned short* __restrict__ tbf,
    float* __restrict__ diag, float* __restrict__ klarr){
  __shared__ float csh[KT];
  int b = blockIdx.x, tid = threadIdx.x, lane = tid & 63, wave = tid >> 6;
  const float* fb = feat + (size_t)b * RR * DD;
  float s2 = lscale[0] * LOG2E;

  // anchor: every wave loads + reduces
  float4 a4 = ((const float4*)fb)[lane];
  float asq = a4.x*a4.x + a4.y*a4.y + a4.z*a4.z + a4.w*a4.w;
  #pragma unroll
  for (int off=1; off<64; off<<=1) asq += __shfl_xor(asq, off);
  float an = fmaxf(sqrtf(asq), EPSV);

  // bf16 anchor out, scaled into log2 domain ([anchor][k] row-major)
  abf[(size_t)b*DD + tid] = f2bf(fb[tid] * s2);

  // target rows: wave w handles kr = w+1, w+5, ...  lane covers k in [4l,4l+4)
  for (int kr = wave+1; kr <= KT; kr += NWAVES){
    float4 t4 = ((const float4*)(fb + (size_t)kr*DD))[lane];
    // fragment-swizzled bf16 store
    int t = b*KT + (kr-1);
    int c = t >> 6, r = t & 63, mt = r >> 5, r31 = r & 31;
    int ks = lane >> 2, h = (lane >> 1) & 1, j0 = (lane & 1) * 4;
    size_t dst = ((size_t)(c*32 + mt*16 + ks))*512 + (size_t)(h*32 + r31)*8 + j0;
    *(ushort4*)(tbf + dst) = make_ushort4(f2bf(t4.x), f2bf(t4.y), f2bf(t4.z), f2bf(t4.w));
    float d = a4.x*t4.x + a4.y*t4.y + a4.z*t4.z + a4.w*t4.w;
    float q = t4.x*t4.x + t4.y*t4.y + t4.z*t4.z + t4.w*t4.w;
    #pragma unroll
    for (int off=1; off<64; off<<=1){ d += __shfl_xor(d,off); q += __shfl_xor(q,off); }
    if (lane == 0){
      csh[kr-1] = d / (an * fmaxf(sqrtf(q), EPSV));
      if (kr == 1) diag[b] = d;
    }
  }
  __syncthreads();
  if (tid == 0){
    float cm = -INFINITY;
    #pragma unroll
    for (int j=0;j<KT;++j) cm = fmaxf(cm, csh[j]);
    float cs = 0.f;
    #pragma unroll
    for (int j=0;j<KT;++j) cs += __builtin_amdgcn_exp2f((csh[j]-cm)*LOG2E);
    float lse_c = cm + __logf(cs);

    const float* sb = scores + (size_t)b*KT;
    float sv[KT];
    #pragma unroll
    for (int j=0;j<KT;++j) sv[j] = sb[j];
    float sm = -INFINITY;
    #pragma unroll
    for (int j=0;j<KT;++j) sm = fmaxf(sm, sv[j]);
    float ss = 0.f;
    #pragma unroll
    for (int j=0;j<KT;++j) ss += __builtin_amdgcn_exp2f((sv[j]-sm)*LOG2E);
    float lse_s = sm + __logf(ss);

    float kl = 0.f;
    #pragma unroll
    for (int j=0;j<KT;++j){
      float lq = sv[j]  - lse_s;
      float lp = csh[j] - lse_c;
      kl += __builtin_amdgcn_exp2f(lq*LOG2E)*(lq - lp);
    }
    klarr[b] = kl * (1.0f/KT);       // no atomic — combine reduces
  }
}

// ---------------- Kernel 2: 32x32x16 MFMA GEMM + online log2-sum-exp2 --------
// Targets staged by linear global_load_lds DMA into fragment-ordered LDS;
// all ds_read_b128 are lane-linear (base + lane*16): conflict-free, peak rate.
// No cross-lane shuffles in the hot loop: per-half-wave (m,s) partials.
__global__ __launch_bounds__(256,2) void gemm_lse_kernel(
    const unsigned short* __restrict__ abf, const unsigned short* __restrict__ tbf,
    float* __restrict__ part_m, float* __restrict__ part_s){
  __shared__ __align__(16) unsigned short Bs[BN*DD];   // 32768 B
  const int tid  = threadIdx.x;
  const int lane = tid & 63;
  const int wave = tid >> 6;
  const int mb   = blockIdx.y;
  const int ns   = blockIdx.x;
  const int l31  = lane & 31;
  const int half = lane >> 5;

  const char* gbase = (const char*)tbf + (size_t)(ns*NSLICE/BN)*CHUNK_BYTES;
  char* lbase = (char*)Bs;
  auto stage = [&](int ch){
    const char* g = gbase + (size_t)ch*CHUNK_BYTES;
    #pragma unroll
    for (int j=0;j<8;++j){
      int off = j*4096 + tid*16;
      gl_lds16(g + off, lbase + off);
    }
  };

  stage(0);   // DMA in flight while we fetch anchor frags

  // anchor B-operand frags (once per block): n=l31, k=half*8+j
  bf16x8 af[2][16];
  {
    const unsigned short* ab = abf + (size_t)(mb*BMB + wave*BMW)*DD;
    #pragma unroll
    for (int nt=0;nt<2;++nt)
      #pragma unroll
      for (int ks=0;ks<16;++ks)
        af[nt][ks] = *(const bf16x8*)(ab + (size_t)(nt*32+l31)*DD + ks*16 + half*8);
  }

  float run_m[2] = {-INFINITY,-INFINITY};
  float run_s[2] = {0.f,0.f};
  const unsigned short* frag = Bs + lane*8;   // lane-linear fragment base

  for (int ch=0; ch<NCHUNK; ++ch){
    __syncthreads();                     // DMA for ch drained

    f32x16 acc[2][2];                    // [mtile(target)][ntile(anchor)]
    #pragma unroll
    for (int mt=0;mt<2;++mt)
      #pragma unroll
      for (int nt=0;nt<2;++nt)
        acc[mt][nt] = (f32x16)(0.f);

    #pragma unroll
    for (int ks=0;ks<16;++ks){
      bf16x8 tf0 = *(const bf16x8*)(frag + (     ks)*512);
      bf16x8 tf1 = *(const bf16x8*)(frag + (16 + ks)*512);
      acc[0][0] = __builtin_amdgcn_mfma_f32_32x32x16_bf16(tf0, af[0][ks], acc[0][0], 0,0,0);
      acc[0][1] = __builtin_amdgcn_mfma_f32_32x32x16_bf16(tf0, af[1][ks], acc[0][1], 0,0,0);
      acc[1][0] = __builtin_amdgcn_mfma_f32_32x32x16_bf16(tf1, af[0][ks], acc[1][0], 0,0,0);
      acc[1][1] = __builtin_amdgcn_mfma_f32_32x32x16_bf16(tf1, af[1][ks], acc[1][1], 0,0,0);
    }
    __syncthreads();                     // all Bs reads done
    if (ch+1 < NCHUNK) stage(ch+1);      // async DMA overlaps register epilogue

    // epilogue (log2 domain): pure in-lane, per half-wave partials
    #pragma unroll
    for (int nt=0;nt<2;++nt){
      f32x16 t = __builtin_elementwise_max(acc[0][nt], acc[1][nt]);
      float m8[8];
      #pragma unroll
      for (int i=0;i<8;++i) m8[i] = fmaxf(t[i], t[i+8]);
      float m4a = fmaxf(m8[0],m8[1]), m4b = fmaxf(m8[2],m8[3]);
      float m4c = fmaxf(m8[4],m8[5]), m4d = fmaxf(m8[6],m8[7]);
      float mx = fmaxf(fmaxf(m4a,m4b), fmaxf(m4c,m4d));

      float s0=0.f, s1=0.f, s2=0.f, s3=0.f;
      #pragma unroll
      for (int r=0;r<16;r+=4){
        s0 += __builtin_amdgcn_exp2f(acc[0][nt][r  ]-mx) + __builtin_amdgcn_exp2f(acc[1][nt][r  ]-mx);
        s1 += __builtin_amdgcn_exp2f(acc[0][nt][r+1]-mx) + __builtin_amdgcn_exp2f(acc[1][nt][r+1]-mx);
        s2 += __builtin_amdgcn_exp2f(acc[0][nt][r+2]-mx) + __builtin_amdgcn_exp2f(acc[1][nt][r+2]-mx);
        s3 += __builtin_amdgcn_exp2f(acc[0][nt][r+3]-mx) + __builtin_amdgcn_exp2f(acc[1][nt][r+3]-mx);
      }
      float sh = (s0+s1)+(s2+s3);

      float nm = fmaxf(run_m[nt], mx);
      run_s[nt] = run_s[nt]*__builtin_amdgcn_exp2f(run_m[nt]-nm)
                + sh*__builtin_amdgcn_exp2f(mx-nm);
      run_m[nt] = nm;
    }
  }

  // all 64 lanes write their half-wave partial
  #pragma unroll
  for (int nt=0;nt<2;++nt){
    int gm = mb*BMB + wave*BMW + nt*32 + l31;
    int slot = ns*2 + half;
    part_m[(size_t)gm*NSLOT + slot] = run_m[nt];
    part_s[(size_t)gm*NSLOT + slot] = run_s[nt];
  }
}

// ---------------- Kernel 3: combine partials + reduce kl -> sums -------------
__global__ __launch_bounds__(256) void combine_kernel(
    const float* __restrict__ part_m, const float* __restrict__ part_s,
    const float* __restrict__ diag, const float* __restrict__ klarr,
    const float* __restrict__ lscale, float* __restrict__ accs){
  int b = blockIdx.x*256 + threadIdx.x;
  float s = lscale[0];
  const float* pm = part_m + (size_t)b*NSLOT;
  const float* ps = part_s + (size_t)b*NSLOT;
  float M = -INFINITY;
  #pragma unroll 8
  for (int i=0;i<NSLOT;++i) M = fmaxf(M, pm[i]);
  float S = 0.f;
  #pragma unroll 8
  for (int i=0;i<NSLOT;++i) S += ps[i]*__builtin_amdgcn_exp2f(pm[i]-M);
  float inf = (M + __log2f(S))*LN2 - s*diag[b];   // back to ln domain
  float kl  = klarr[b];
  #pragma unroll
  for (int off=1; off<64; off<<=1){
    inf += __shfl_xor(inf, off);
    kl  += __shfl_xor(kl,  off);
  }
  if ((threadIdx.x & 63)==0){
    atomicAdd(accs+1, inf);
    atomicAdd(accs+0, kl);
  }
}

// ---------------- Kernel 4: final scalar ------------------------------------
__global__ void final_kernel(const float* __restrict__ accs, float* __restrict__ out){
  out[0] = BETA*(accs[0]*(1.0f/BATCH)) + ALPHA*(accs[1]*(1.0f/BATCH));
}

extern "C" void kernel_launch(void* const* d_in, const int* in_sizes, int n_in,
                              void* d_out, int out_size, void* d_ws, size_t ws_size,
                              hipStream_t stream){
  const float* feat   = (const float*)d_in[0];
  const float* scores = (const float*)d_in[1];
  // d_in[2] row_sizes: shape-only, unused
  const float* lscale = (const float*)d_in[3];

  float* ws     = (float*)d_ws;
  float* diag   = ws;                                   // 4096
  float* klarr  = diag + BATCH;                         // 4096
  float* part_m = klarr + BATCH;                        // 4096*64
  float* part_s = part_m + (size_t)BATCH*NSLOT;         // 4096*64
  float* accs   = part_s + (size_t)BATCH*NSLOT;         // 4
  unsigned short* abf = (unsigned short*)(accs + 4);    // 4096*256 bf16
  unsigned short* tbf = abf + (size_t)BATCH*DD;         // 69632*256 bf16, frag-ordered

  hipMemsetAsync(accs, 0, 2*sizeof(float), stream);
  prep_kernel<<<BATCH, 256, 0, stream>>>(feat, scores, lscale, abf, tbf, diag, klarr);
  gemm_lse_kernel<<<dim3(NSPLIT, MBLK), 256, 0, stream>>>(abf, tbf, part_m, part_s);
  combine_kernel<<<BATCH/256, 256, 0, stream>>>(part_m, part_s, diag, klarr, lscale, accs);
  final_kernel<<<1,1,0,stream>>>(accs, (float*)d_out);
}

// Round 5
// 216.561 us; speedup vs baseline: 1.6552x; 1.2813x over previous
//
#include <hip/hip_runtime.h>
#include <math.h>

#define ALPHA 0.2f
#define BETA 1.0f
#define EPSV 1e-8f
#define LOG2E 1.4426950408889634f
#define LN2 0.6931471805599453f

#define BATCH 4096
#define RR 18
#define KT 17            // R-1 targets per row
#define DD 256
#define NTGT (BATCH*KT)  // 69632 total targets

#define BMW 64           // anchors per wave (2 x 32-tiles, frags in registers)
#define NWAVES 4
#define BMB (BMW*NWAVES) // 256 anchors per block
#define MBLK (BATCH/BMB) // 16
#define BN 64            // targets per LDS chunk
#define NSPLIT 32        // N-dimension splits
#define NSLOT (NSPLIT*2) // per-anchor partial slots (x2: per half-wave)
#define NSLICE (NTGT/NSPLIT) // 2176
#define NCHUNK (NSLICE/BN)   // 34
#define CHUNK_BYTES (BN*DD)      // 16384 fp8 bytes, fragment-ordered
#define TSH_STRIDE 272           // prep LDS row stride (16-B aligned, spreads banks)

typedef int   i32x8  __attribute__((ext_vector_type(8)));
typedef float f32x16 __attribute__((ext_vector_type(16)));

__device__ inline void gl_lds16(const void* g, void* l){
  __builtin_amdgcn_global_load_lds(
      (const __attribute__((address_space(1))) unsigned int*)g,
      (__attribute__((address_space(3))) unsigned int*)l, 16, 0, 0);
}

// tbf8 fragment layout (fp8 e4m3): target t -> chunk c=t>>6, r=t&63,
// mt=r>>5, m=r&31.  K split: ki=k>>6 (4), half=(k>>5)&1, w=(k>>4)&1, b=k&15.
// 1-KB region id (ki*2+mt)*2+w inside chunk; 16-B slot (half*32+m) inside
// region.  Gemm lane l (m=l&31, half=l>>5) reads its 16 B at region*1024 +
// lane-linear offset -> conflict-free ds_read_b128.  Chunk = 16 KB linear.

// ---------------- Kernel 1: convert->fp8 (coalesced) + KL + diag -------------
__global__ __launch_bounds__(256) void prep_kernel(
    const float* __restrict__ feat, const float* __restrict__ scores,
    const float* __restrict__ lscale,
    unsigned char* __restrict__ abf8, unsigned char* __restrict__ tbf8,
    float* __restrict__ diag, float* __restrict__ klarr){
  __shared__ float csh[KT];
  __shared__ __align__(16) unsigned char tsh[KT*TSH_STRIDE];
  int b = blockIdx.x, tid = threadIdx.x, lane = tid & 63, wave = tid >> 6;
  const float* fb = feat + (size_t)b * RR * DD;
  float s2 = lscale[0] * LOG2E;

  // anchor: every wave loads + reduces norm
  float4 a4 = ((const float4*)fb)[lane];
  float asq = a4.x*a4.x + a4.y*a4.y + a4.z*a4.z + a4.w*a4.w;
  #pragma unroll
  for (int off=1; off<64; off<<=1) asq += __shfl_xor(asq, off);
  float an = fmaxf(sqrtf(asq), EPSV);

  if (wave == 0){  // fp8 anchor out, scaled into log2 domain (coalesced 4B)
    int p = __builtin_amdgcn_cvt_pk_fp8_f32(a4.x*s2, a4.y*s2, 0, false);
    p     = __builtin_amdgcn_cvt_pk_fp8_f32(a4.z*s2, a4.w*s2, p, true);
    *(int*)(abf8 + (size_t)b*DD + lane*4) = p;
  }

  // target rows: wave w handles kr = w+1, w+5, ...; fp8 rows to LDS
  for (int kr = wave+1; kr <= KT; kr += NWAVES){
    float4 t4 = ((const float4*)(fb + (size_t)kr*DD))[lane];
    int p = __builtin_amdgcn_cvt_pk_fp8_f32(t4.x, t4.y, 0, false);
    p     = __builtin_amdgcn_cvt_pk_fp8_f32(t4.z, t4.w, p, true);
    *(int*)&tsh[(kr-1)*TSH_STRIDE + lane*4] = p;
    float d = a4.x*t4.x + a4.y*t4.y + a4.z*t4.z + a4.w*t4.w;
    float q = t4.x*t4.x + t4.y*t4.y + t4.z*t4.z + t4.w*t4.w;
    #pragma unroll
    for (int off=1; off<64; off<<=1){ d += __shfl_xor(d,off); q += __shfl_xor(q,off); }
    if (lane == 0){
      csh[kr-1] = d / (an * fmaxf(sqrtf(q), EPSV));
      if (kr == 1) diag[b] = d;
    }
  }
  __syncthreads();

  // coalesced fragment store-out: 17 targets x 16 k-pieces of 16 B
  for (int idx = tid; idx < KT*16; idx += 256){
    int g = idx / KT;            // k-piece 0..15 = ki*4 + half*2 + w
    int j = idx - g*KT;          // target-in-row 0..16 (consecutive per g)
    int ki = g >> 2, half = (g >> 1) & 1, w = g & 1;
    int t  = b*KT + j;
    int c  = t >> 6, r = t & 63, mt = (r >> 5) & 1, m = r & 31;
    uint4 v = *(const uint4*)&tsh[j*TSH_STRIDE + ki*64 + half*32 + w*16];
    size_t dst = (size_t)c*CHUNK_BYTES + (size_t)((ki*2+mt)*2 + w)*1024
               + half*512 + m*16;
    *(uint4*)(tbf8 + dst) = v;
  }

  if (tid == 0){
    float cm = -INFINITY;
    #pragma unroll
    for (int j=0;j<KT;++j) cm = fmaxf(cm, csh[j]);
    float cs = 0.f;
    #pragma unroll
    for (int j=0;j<KT;++j) cs += __builtin_amdgcn_exp2f((csh[j]-cm)*LOG2E);
    float lse_c = cm + __logf(cs);

    const float* sb = scores + (size_t)b*KT;
    float sv[KT];
    #pragma unroll
    for (int j=0;j<KT;++j) sv[j] = sb[j];
    float sm = -INFINITY;
    #pragma unroll
    for (int j=0;j<KT;++j) sm = fmaxf(sm, sv[j]);
    float ss = 0.f;
    #pragma unroll
    for (int j=0;j<KT;++j) ss += __builtin_amdgcn_exp2f((sv[j]-sm)*LOG2E);
    float lse_s = sm + __logf(ss);

    float kl = 0.f;
    #pragma unroll
    for (int j=0;j<KT;++j){
      float lq = sv[j]  - lse_s;
      float lp = csh[j] - lse_c;
      kl += __builtin_amdgcn_exp2f(lq*LOG2E)*(lq - lp);
    }
    klarr[b] = kl * (1.0f/KT);
  }
}

// ---------------- Kernel 2: MX-fp8 32x32x64 MFMA + online log2-sum-exp2 ------
// D[m=target][n=anchor], scales fixed at 1.0 (e8m0 127). Double-buffered LDS,
// ONE barrier per chunk; DMA for ch+1 issued right after the barrier so it has
// the whole MFMA+epilogue window to land.
__global__ __launch_bounds__(256,2) void gemm_lse_kernel(
    const unsigned char* __restrict__ abf8, const unsigned char* __restrict__ tbf8,
    float* __restrict__ part_m, float* __restrict__ part_s){
  __shared__ __align__(16) unsigned char Bs[2][CHUNK_BYTES];   // 2 x 16 KB
  const int tid  = threadIdx.x;
  const int lane = tid & 63;
  const int wave = tid >> 6;
  const int mb   = blockIdx.y;
  const int ns   = blockIdx.x;
  const int l31  = lane & 31;
  const int half = lane >> 5;

  const char* gbase = (const char*)tbf8 + (size_t)(ns*NCHUNK)*CHUNK_BYTES;
  auto stage = [&](int ch){
    const char* g = gbase + (size_t)ch*CHUNK_BYTES;
    char* l = (char*)Bs[ch & 1];
    #pragma unroll
    for (int j=0;j<4;++j){
      int off = j*4096 + tid*16;
      gl_lds16(g + off, l + off);
    }
  };

  stage(0);   // DMA in flight while we fetch anchor frags

  // anchor B-operand frags (once per block): n=l31, k=half*32+byte, per ki
  i32x8 af[2][4];
  {
    const unsigned char* ab = abf8 + (size_t)(mb*BMB + wave*BMW)*DD;
    #pragma unroll
    for (int nt=0;nt<2;++nt)
      #pragma unroll
      for (int ki=0;ki<4;++ki){
        const unsigned char* p = ab + (size_t)(nt*32+l31)*DD + ki*64 + half*32;
        uint4 lo = *(const uint4*)p;
        uint4 hi = *(const uint4*)(p+16);
        af[nt][ki] = (i32x8){(int)lo.x,(int)lo.y,(int)lo.z,(int)lo.w,
                             (int)hi.x,(int)hi.y,(int)hi.z,(int)hi.w};
      }
  }

  float run_m[2] = {-INFINITY,-INFINITY};
  float run_s[2] = {0.f,0.f};

  for (int ch=0; ch<NCHUNK; ++ch){
    __syncthreads();                   // DMA for ch drained; buf[ch^1] reads done
    if (ch+1 < NCHUNK) stage(ch+1);    // async DMA into other buffer

    const unsigned char* frag = &Bs[ch & 1][0] + lane*16;

    f32x16 acc[2][2];
    #pragma unroll
    for (int mt=0;mt<2;++mt)
      #pragma unroll
      for (int nt=0;nt<2;++nt)
        acc[mt][nt] = (f32x16)(0.f);

    #pragma unroll
    for (int ki=0;ki<4;++ki){
      i32x8 tf[2];
      #pragma unroll
      for (int mt=0;mt<2;++mt){
        uint4 lo = *(const uint4*)(frag + (size_t)((ki*2+mt)*2+0)*1024);
        uint4 hi = *(const uint4*)(frag + (size_t)((ki*2+mt)*2+1)*1024);
        tf[mt] = (i32x8){(int)lo.x,(int)lo.y,(int)lo.z,(int)lo.w,
                         (int)hi.x,(int)hi.y,(int)hi.z,(int)hi.w};
      }
      acc[0][0] = __builtin_amdgcn_mfma_scale_f32_32x32x64_f8f6f4(
                      tf[0], af[0][ki], acc[0][0], 0,0, 0,127, 0,127);
      acc[0][1] = __builtin_amdgcn_mfma_scale_f32_32x32x64_f8f6f4(
                      tf[0], af[1][ki], acc[0][1], 0,0, 0,127, 0,127);
      acc[1][0] = __builtin_amdgcn_mfma_scale_f32_32x32x64_f8f6f4(
                      tf[1], af[0][ki], acc[1][0], 0,0, 0,127, 0,127);
      acc[1][1] = __builtin_amdgcn_mfma_scale_f32_32x32x64_f8f6f4(
                      tf[1], af[1][ki], acc[1][1], 0,0, 0,127, 0,127);
    }

    // epilogue (log2 domain): pure in-lane, per half-wave partials
    #pragma unroll
    for (int nt=0;nt<2;++nt){
      f32x16 t = __builtin_elementwise_max(acc[0][nt], acc[1][nt]);
      float m8[8];
      #pragma unroll
      for (int i=0;i<8;++i) m8[i] = fmaxf(t[i], t[i+8]);
      float m4a = fmaxf(m8[0],m8[1]), m4b = fmaxf(m8[2],m8[3]);
      float m4c = fmaxf(m8[4],m8[5]), m4d = fmaxf(m8[6],m8[7]);
      float mx = fmaxf(fmaxf(m4a,m4b), fmaxf(m4c,m4d));

      float s0=0.f, s1=0.f, s2=0.f, s3=0.f;
      #pragma unroll
      for (int r=0;r<16;r+=4){
        s0 += __builtin_amdgcn_exp2f(acc[0][nt][r  ]-mx) + __builtin_amdgcn_exp2f(acc[1][nt][r  ]-mx);
        s1 += __builtin_amdgcn_exp2f(acc[0][nt][r+1]-mx) + __builtin_amdgcn_exp2f(acc[1][nt][r+1]-mx);
        s2 += __builtin_amdgcn_exp2f(acc[0][nt][r+2]-mx) + __builtin_amdgcn_exp2f(acc[1][nt][r+2]-mx);
        s3 += __builtin_amdgcn_exp2f(acc[0][nt][r+3]-mx) + __builtin_amdgcn_exp2f(acc[1][nt][r+3]-mx);
      }
      float sh = (s0+s1)+(s2+s3);

      float nm = fmaxf(run_m[nt], mx);
      run_s[nt] = run_s[nt]*__builtin_amdgcn_exp2f(run_m[nt]-nm)
                + sh*__builtin_amdgcn_exp2f(mx-nm);
      run_m[nt] = nm;
    }
  }

  #pragma unroll
  for (int nt=0;nt<2;++nt){
    int gm = mb*BMB + wave*BMW + nt*32 + l31;
    int slot = ns*2 + half;
    part_m[(size_t)gm*NSLOT + slot] = run_m[nt];
    part_s[(size_t)gm*NSLOT + slot] = run_s[nt];
  }
}

// ---------------- Kernel 3: combine partials + reduce kl -> sums -------------
__global__ __launch_bounds__(256) void combine_kernel(
    const float* __restrict__ part_m, const float* __restrict__ part_s,
    const float* __restrict__ diag, const float* __restrict__ klarr,
    const float* __restrict__ lscale, float* __restrict__ accs){
  int b = blockIdx.x*256 + threadIdx.x;
  float s = lscale[0];
  const float* pm = part_m + (size_t)b*NSLOT;
  const float* ps = part_s + (size_t)b*NSLOT;
  float M = -INFINITY;
  #pragma unroll 8
  for (int i=0;i<NSLOT;++i) M = fmaxf(M, pm[i]);
  float S = 0.f;
  #pragma unroll 8
  for (int i=0;i<NSLOT;++i) S += ps[i]*__builtin_amdgcn_exp2f(pm[i]-M);
  float inf = (M + __log2f(S))*LN2 - s*diag[b];   // back to ln domain
  float kl  = klarr[b];
  #pragma unroll
  for (int off=1; off<64; off<<=1){
    inf += __shfl_xor(inf, off);
    kl  += __shfl_xor(kl,  off);
  }
  if ((threadIdx.x & 63)==0){
    atomicAdd(accs+1, inf);
    atomicAdd(accs+0, kl);
  }
}

// ---------------- Kernel 4: final scalar ------------------------------------
__global__ void final_kernel(const float* __restrict__ accs, float* __restrict__ out){
  out[0] = BETA*(accs[0]*(1.0f/BATCH)) + ALPHA*(accs[1]*(1.0f/BATCH));
}

extern "C" void kernel_launch(void* const* d_in, const int* in_sizes, int n_in,
                              void* d_out, int out_size, void* d_ws, size_t ws_size,
                              hipStream_t stream){
  const float* feat   = (const float*)d_in[0];
  const float* scores = (const float*)d_in[1];
  // d_in[2] row_sizes: shape-only, unused
  const float* lscale = (const float*)d_in[3];

  float* ws     = (float*)d_ws;
  float* diag   = ws;                                   // 4096
  float* klarr  = diag + BATCH;                         // 4096
  float* part_m = klarr + BATCH;                        // 4096*64
  float* part_s = part_m + (size_t)BATCH*NSLOT;         // 4096*64
  float* accs   = part_s + (size_t)BATCH*NSLOT;         // 4
  unsigned char* abf8 = (unsigned char*)(accs + 4);     // 4096*256 fp8
  unsigned char* tbf8 = abf8 + (size_t)BATCH*DD;        // 69632*256 fp8, frag-ordered

  hipMemsetAsync(accs, 0, 2*sizeof(float), stream);
  prep_kernel<<<BATCH, 256, 0, stream>>>(feat, scores, lscale, abf8, tbf8, diag, klarr);
  gemm_lse_kernel<<<dim3(NSPLIT, MBLK), 256, 0, stream>>>(abf8, tbf8, part_m, part_s);
  combine_kernel<<<BATCH/256, 256, 0, stream>>>(part_m, part_s, diag, klarr, lscale, accs);
  final_kernel<<<1,1,0,stream>>>(accs, (float*)d_out);
}

// Round 6
// 198.593 us; speedup vs baseline: 1.8049x; 1.0905x over previous
//
#include <hip/hip_runtime.h>
#include <math.h>

#define ALPHA 0.2f
#define BETA 1.0f
#define EPSV 1e-8f
#define LOG2E 1.4426950408889634f
#define LN2 0.6931471805599453f

#define BATCH 4096
#define RR 18
#define KT 17            // R-1 targets per row
#define DD 256
#define NTGT (BATCH*KT)  // 69632 total targets

#define BMW 64           // anchors per wave (2 x 32-tiles, frags in registers)
#define NWAVES 4
#define BMB (BMW*NWAVES) // 256 anchors per block
#define MBLK (BATCH/BMB) // 16
#define BN 64            // targets per LDS chunk
#define NSPLIT 64        // N-dimension splits (grid 1024 = ~3-4 blocks/CU, desynced)
#define NSLOT (NSPLIT*2) // per-anchor partial slots (x2: per half-wave)
#define NSLICE (NTGT/NSPLIT) // 1088
#define NCHUNK (NSLICE/BN)   // 17
#define CHUNK_BYTES (BN*DD)      // 16384 fp8 bytes, fragment-ordered

typedef int   i32x8  __attribute__((ext_vector_type(8)));
typedef float f32x16 __attribute__((ext_vector_type(16)));

__device__ inline void gl_lds16(const void* g, void* l){
  __builtin_amdgcn_global_load_lds(
      (const __attribute__((address_space(1))) unsigned int*)g,
      (__attribute__((address_space(3))) unsigned int*)l, 16, 0, 0);
}

__device__ inline int pk8(float a, float b, float c, float d){
  int p = __builtin_amdgcn_cvt_pk_fp8_f32(a, b, 0, false);
  return  __builtin_amdgcn_cvt_pk_fp8_f32(c, d, p, true);
}

// tbf8 fragment layout (fp8 e4m3): target t -> chunk c=t>>6, r=t&63,
// mt=r>>5, m=r&31.  K split: ki=k>>6 (4), half=(k>>5)&1, w=(k>>4)&1.
// 1-KB region (ki*2+mt)*2+w inside chunk; 16-B slot (half*32+m).
// Gemm lane l (m=l&31, half=l>>5) reads lane-linear -> conflict-free b128.

// ---------------- Kernel 1: convert->fp8 + KL + diag -------------------------
// 256 threads = 16 groups of 16 lanes; group g handles target rows g+1, g+17.
// Each lane owns 16 contiguous k (one 16-B fp8 fragment slot) -> direct store.
__global__ __launch_bounds__(256) void prep_kernel(
    const float* __restrict__ feat, const float* __restrict__ scores,
    const float* __restrict__ lscale,
    unsigned char* __restrict__ abf8, unsigned char* __restrict__ tbf8,
    float* __restrict__ diag, float* __restrict__ klarr){
  __shared__ float csh[KT];
  int b = blockIdx.x, tid = threadIdx.x;
  int grp = tid >> 4, j = tid & 15;
  const float* fb = feat + (size_t)b * RR * DD;
  float s2 = lscale[0] * LOG2E;

  // anchor: each lane loads its 16 k-values (same across groups -> L1 broadcast)
  float4 a0 = ((const float4*)fb)[j*4+0];
  float4 a1 = ((const float4*)fb)[j*4+1];
  float4 a2 = ((const float4*)fb)[j*4+2];
  float4 a3 = ((const float4*)fb)[j*4+3];
  float asq = (a0.x*a0.x+a0.y*a0.y+a0.z*a0.z+a0.w*a0.w)
            + (a1.x*a1.x+a1.y*a1.y+a1.z*a1.z+a1.w*a1.w)
            + (a2.x*a2.x+a2.y*a2.y+a2.z*a2.z+a2.w*a2.w)
            + (a3.x*a3.x+a3.y*a3.y+a3.z*a3.z+a3.w*a3.w);
  #pragma unroll
  for (int off=1; off<16; off<<=1) asq += __shfl_xor(asq, off);
  float an = fmaxf(sqrtf(asq), EPSV);

  if (tid < 16){   // anchor fp8 out (scaled into log2 domain), 16 B per lane
    uint4 v = make_uint4(
      (unsigned)pk8(a0.x*s2,a0.y*s2,a0.z*s2,a0.w*s2),
      (unsigned)pk8(a1.x*s2,a1.y*s2,a1.z*s2,a1.w*s2),
      (unsigned)pk8(a2.x*s2,a2.y*s2,a2.z*s2,a2.w*s2),
      (unsigned)pk8(a3.x*s2,a3.y*s2,a3.z*s2,a3.w*s2));
    *(uint4*)(abf8 + (size_t)b*DD + j*16) = v;
  }

  for (int kr = grp+1; kr <= KT; kr += 16){
    const float4* tp = (const float4*)(fb + (size_t)kr*DD) + j*4;
    float4 t0=tp[0], t1=tp[1], t2=tp[2], t3=tp[3];
    // fp8 fragment store: lane j holds k in [j*16, j*16+16)
    int t  = b*KT + (kr-1);
    int c  = t >> 6, r = t & 63, mt = (r >> 5) & 1, m = r & 31;
    int ki = j >> 2, hf = (j >> 1) & 1, w = j & 1;
    uint4 v = make_uint4(
      (unsigned)pk8(t0.x,t0.y,t0.z,t0.w), (unsigned)pk8(t1.x,t1.y,t1.z,t1.w),
      (unsigned)pk8(t2.x,t2.y,t2.z,t2.w), (unsigned)pk8(t3.x,t3.y,t3.z,t3.w));
    *(uint4*)(tbf8 + (size_t)c*CHUNK_BYTES + (size_t)((ki*2+mt)*2+w)*1024
              + hf*512 + m*16) = v;
    float d = (a0.x*t0.x+a0.y*t0.y+a0.z*t0.z+a0.w*t0.w)
            + (a1.x*t1.x+a1.y*t1.y+a1.z*t1.z+a1.w*t1.w)
            + (a2.x*t2.x+a2.y*t2.y+a2.z*t2.z+a2.w*t2.w)
            + (a3.x*t3.x+a3.y*t3.y+a3.z*t3.z+a3.w*t3.w);
    float q = (t0.x*t0.x+t0.y*t0.y+t0.z*t0.z+t0.w*t0.w)
            + (t1.x*t1.x+t1.y*t1.y+t1.z*t1.z+t1.w*t1.w)
            + (t2.x*t2.x+t2.y*t2.y+t2.z*t2.z+t2.w*t2.w)
            + (t3.x*t3.x+t3.y*t3.y+t3.z*t3.z+t3.w*t3.w);
    #pragma unroll
    for (int off=1; off<16; off<<=1){ d += __shfl_xor(d,off); q += __shfl_xor(q,off); }
    if (j == 0){
      csh[kr-1] = d / (an * fmaxf(sqrtf(q), EPSV));
      if (kr == 1) diag[b] = d;
    }
  }
  __syncthreads();

  if (tid == 0){
    float cm = -INFINITY;
    #pragma unroll
    for (int i=0;i<KT;++i) cm = fmaxf(cm, csh[i]);
    float cs = 0.f;
    #pragma unroll
    for (int i=0;i<KT;++i) cs += __builtin_amdgcn_exp2f((csh[i]-cm)*LOG2E);
    float lse_c = cm + __logf(cs);

    const float* sb = scores + (size_t)b*KT;
    float sv[KT];
    #pragma unroll
    for (int i=0;i<KT;++i) sv[i] = sb[i];
    float sm = -INFINITY;
    #pragma unroll
    for (int i=0;i<KT;++i) sm = fmaxf(sm, sv[i]);
    float ss = 0.f;
    #pragma unroll
    for (int i=0;i<KT;++i) ss += __builtin_amdgcn_exp2f((sv[i]-sm)*LOG2E);
    float lse_s = sm + __logf(ss);

    float kl = 0.f;
    #pragma unroll
    for (int i=0;i<KT;++i){
      float lq = sv[i]  - lse_s;
      float lp = csh[i] - lse_c;
      kl += __builtin_amdgcn_exp2f(lq*LOG2E)*(lq - lp);
    }
    klarr[b] = kl * (1.0f/KT);
  }
}

// ---------------- Kernel 2: MX-fp8 32x32x64 MFMA + online log2-sum-exp2 ------
// D[m=target][n=anchor], scales=1.0 (e8m0 127). Double-buffered LDS, one
// barrier per chunk. 3 waves/SIMD (launch_bounds 256,3) so independent blocks
// overlap MFMA with epilogue VALU.
__global__ __launch_bounds__(256,3) void gemm_lse_kernel(
    const unsigned char* __restrict__ abf8, const unsigned char* __restrict__ tbf8,
    float* __restrict__ part_m, float* __restrict__ part_s){
  __shared__ __align__(16) unsigned char Bs[2][CHUNK_BYTES];   // 2 x 16 KB
  const int tid  = threadIdx.x;
  const int lane = tid & 63;
  const int wave = tid >> 6;
  const int mb   = blockIdx.y;
  const int ns   = blockIdx.x;
  const int l31  = lane & 31;
  const int half = lane >> 5;

  const char* gbase = (const char*)tbf8 + (size_t)(ns*NCHUNK)*CHUNK_BYTES;
  auto stage = [&](int ch){
    const char* g = gbase + (size_t)ch*CHUNK_BYTES;
    char* l = (char*)Bs[ch & 1];
    #pragma unroll
    for (int j=0;j<4;++j){
      int off = j*4096 + tid*16;
      gl_lds16(g + off, l + off);
    }
  };

  stage(0);   // DMA in flight while we fetch anchor frags

  // anchor B-operand frags (once per block): n=l31, k=half*32+byte, per ki
  i32x8 af[2][4];
  {
    const unsigned char* ab = abf8 + (size_t)(mb*BMB + wave*BMW)*DD;
    #pragma unroll
    for (int nt=0;nt<2;++nt)
      #pragma unroll
      for (int ki=0;ki<4;++ki){
        const unsigned char* p = ab + (size_t)(nt*32+l31)*DD + ki*64 + half*32;
        uint4 lo = *(const uint4*)p;
        uint4 hi = *(const uint4*)(p+16);
        af[nt][ki] = (i32x8){(int)lo.x,(int)lo.y,(int)lo.z,(int)lo.w,
                             (int)hi.x,(int)hi.y,(int)hi.z,(int)hi.w};
      }
  }

  float run_m[2] = {-INFINITY,-INFINITY};
  float run_s[2] = {0.f,0.f};

  for (int ch=0; ch<NCHUNK; ++ch){
    __syncthreads();                   // DMA for ch drained; buf[ch^1] reads done
    if (ch+1 < NCHUNK) stage(ch+1);    // async DMA into other buffer

    const unsigned char* frag = &Bs[ch & 1][0] + lane*16;

    f32x16 acc[2][2];
    #pragma unroll
    for (int mt=0;mt<2;++mt)
      #pragma unroll
      for (int nt=0;nt<2;++nt)
        acc[mt][nt] = (f32x16)(0.f);

    #pragma unroll
    for (int ki=0;ki<4;++ki){
      i32x8 tf[2];
      #pragma unroll
      for (int mt=0;mt<2;++mt){
        uint4 lo = *(const uint4*)(frag + (size_t)((ki*2+mt)*2+0)*1024);
        uint4 hi = *(const uint4*)(frag + (size_t)((ki*2+mt)*2+1)*1024);
        tf[mt] = (i32x8){(int)lo.x,(int)lo.y,(int)lo.z,(int)lo.w,
                         (int)hi.x,(int)hi.y,(int)hi.z,(int)hi.w};
      }
      acc[0][0] = __builtin_amdgcn_mfma_scale_f32_32x32x64_f8f6f4(
                      tf[0], af[0][ki], acc[0][0], 0,0, 0,127, 0,127);
      acc[0][1] = __builtin_amdgcn_mfma_scale_f32_32x32x64_f8f6f4(
                      tf[0], af[1][ki], acc[0][1], 0,0, 0,127, 0,127);
      acc[1][0] = __builtin_amdgcn_mfma_scale_f32_32x32x64_f8f6f4(
                      tf[1], af[0][ki], acc[1][0], 0,0, 0,127, 0,127);
      acc[1][1] = __builtin_amdgcn_mfma_scale_f32_32x32x64_f8f6f4(
                      tf[1], af[1][ki], acc[1][1], 0,0, 0,127, 0,127);
    }

    // epilogue (log2 domain): pure in-lane, per half-wave partials
    #pragma unroll
    for (int nt=0;nt<2;++nt){
      f32x16 t = __builtin_elementwise_max(acc[0][nt], acc[1][nt]);
      float m8[8];
      #pragma unroll
      for (int i=0;i<8;++i) m8[i] = fmaxf(t[i], t[i+8]);
      float m4a = fmaxf(m8[0],m8[1]), m4b = fmaxf(m8[2],m8[3]);
      float m4c = fmaxf(m8[4],m8[5]), m4d = fmaxf(m8[6],m8[7]);
      float mx = fmaxf(fmaxf(m4a,m4b), fmaxf(m4c,m4d));

      float s0=0.f, s1=0.f, s2=0.f, s3=0.f;
      #pragma unroll
      for (int r=0;r<16;r+=4){
        s0 += __builtin_amdgcn_exp2f(acc[0][nt][r  ]-mx) + __builtin_amdgcn_exp2f(acc[1][nt][r  ]-mx);
        s1 += __builtin_amdgcn_exp2f(acc[0][nt][r+1]-mx) + __builtin_amdgcn_exp2f(acc[1][nt][r+1]-mx);
        s2 += __builtin_amdgcn_exp2f(acc[0][nt][r+2]-mx) + __builtin_amdgcn_exp2f(acc[1][nt][r+2]-mx);
        s3 += __builtin_amdgcn_exp2f(acc[0][nt][r+3]-mx) + __builtin_amdgcn_exp2f(acc[1][nt][r+3]-mx);
      }
      float sh = (s0+s1)+(s2+s3);

      float nm = fmaxf(run_m[nt], mx);
      run_s[nt] = run_s[nt]*__builtin_amdgcn_exp2f(run_m[nt]-nm)
                + sh*__builtin_amdgcn_exp2f(mx-nm);
      run_m[nt] = nm;
    }
  }

  #pragma unroll
  for (int nt=0;nt<2;++nt){
    int gm = mb*BMB + wave*BMW + nt*32 + l31;
    int slot = ns*2 + half;
    part_m[(size_t)gm*NSLOT + slot] = run_m[nt];
    part_s[(size_t)gm*NSLOT + slot] = run_s[nt];
  }
}

// ---------------- Kernel 3: combine partials (one wave per b) ----------------
__global__ __launch_bounds__(256) void combine_kernel(
    const float* __restrict__ part_m, const float* __restrict__ part_s,
    const float* __restrict__ diag, const float* __restrict__ lscale,
    float* __restrict__ infarr){
  int lane = threadIdx.x & 63, wave = threadIdx.x >> 6;
  int b = blockIdx.x*4 + wave;
  float s = lscale[0];
  const float* pm = part_m + (size_t)b*NSLOT;
  const float* ps = part_s + (size_t)b*NSLOT;
  float m0 = pm[lane], m1 = pm[lane+64];
  float v0 = ps[lane], v1 = ps[lane+64];
  float M = fmaxf(m0, m1);
  #pragma unroll
  for (int off=1; off<64; off<<=1) M = fmaxf(M, __shfl_xor(M, off));
  float S = v0*__builtin_amdgcn_exp2f(m0-M) + v1*__builtin_amdgcn_exp2f(m1-M);
  #pragma unroll
  for (int off=1; off<64; off<<=1) S += __shfl_xor(S, off);
  if (lane == 0)
    infarr[b] = (M + __log2f(S))*LN2 - s*diag[b];   // back to ln domain
}

// ---------------- Kernel 4: final reduction (no atomics) ---------------------
__global__ __launch_bounds__(256) void final_kernel(
    const float* __restrict__ infarr, const float* __restrict__ klarr,
    float* __restrict__ out){
  __shared__ float shi[4], shk[4];
  int tid = threadIdx.x, lane = tid & 63, wave = tid >> 6;
  float inf = 0.f, kl = 0.f;
  for (int i = tid; i < BATCH; i += 256){ inf += infarr[i]; kl += klarr[i]; }
  #pragma unroll
  for (int off=1; off<64; off<<=1){
    inf += __shfl_xor(inf, off);
    kl  += __shfl_xor(kl,  off);
  }
  if (lane == 0){ shi[wave] = inf; shk[wave] = kl; }
  __syncthreads();
  if (tid == 0){
    float I = shi[0]+shi[1]+shi[2]+shi[3];
    float K = shk[0]+shk[1]+shk[2]+shk[3];
    out[0] = BETA*(K*(1.0f/BATCH)) + ALPHA*(I*(1.0f/BATCH));
  }
}

extern "C" void kernel_launch(void* const* d_in, const int* in_sizes, int n_in,
                              void* d_out, int out_size, void* d_ws, size_t ws_size,
                              hipStream_t stream){
  const float* feat   = (const float*)d_in[0];
  const float* scores = (const float*)d_in[1];
  // d_in[2] row_sizes: shape-only, unused
  const float* lscale = (const float*)d_in[3];

  float* ws     = (float*)d_ws;
  float* diag   = ws;                                   // 4096
  float* klarr  = diag + BATCH;                         // 4096
  float* infarr = klarr + BATCH;                        // 4096
  float* part_m = infarr + BATCH;                       // 4096*128
  float* part_s = part_m + (size_t)BATCH*NSLOT;         // 4096*128
  unsigned char* abf8 = (unsigned char*)(part_s + (size_t)BATCH*NSLOT);
  unsigned char* tbf8 = abf8 + (size_t)BATCH*DD;        // 69632*256 fp8, frag-ordered

  prep_kernel<<<BATCH, 256, 0, stream>>>(feat, scores, lscale, abf8, tbf8, diag, klarr);
  gemm_lse_kernel<<<dim3(NSPLIT, MBLK), 256, 0, stream>>>(abf8, tbf8, part_m, part_s);
  combine_kernel<<<BATCH/4, 256, 0, stream>>>(part_m, part_s, diag, lscale, infarr);
  final_kernel<<<1, 256, 0, stream>>>(infarr, klarr, (float*)d_out);
}